// Round 21
// baseline (135.166 us; speedup 1.0000x reference)
//
#include <hip/hip_runtime.h>
#include <hip/hip_bf16.h>

typedef __bf16 bf16x8 __attribute__((ext_vector_type(8)));
typedef float  f32x4  __attribute__((ext_vector_type(4)));
typedef unsigned short u16;

__device__ __forceinline__ u16 f2bf(float f) {
    __bf16 h = (__bf16)f;
    return __builtin_bit_cast(u16, h);
}

__device__ __forceinline__ f32x4 mfma16(bf16x8 a, bf16x8 b, f32x4 c) {
    return __builtin_amdgcn_mfma_f32_16x16x32_bf16(a, b, c, 0, 0, 0);
}

__device__ __forceinline__ bf16x8 cvt8(float4 a0, float4 a1) {
    bf16x8 u;
    u[0] = (__bf16)a0.x; u[1] = (__bf16)a0.y; u[2] = (__bf16)a0.z; u[3] = (__bf16)a0.w;
    u[4] = (__bf16)a1.x; u[5] = (__bf16)a1.y; u[6] = (__bf16)a1.z; u[7] = (__bf16)a1.w;
    return u;
}

// async global->LDS, 16B per lane. LDS dest = wave-uniform base + lane*16.
__device__ __forceinline__ void gload16(const u16* g, u16* l) {
    __builtin_amdgcn_global_load_lds(
        (const __attribute__((address_space(1))) void*)g,
        (__attribute__((address_space(3))) void*)l, 16, 0, 0);
}

// ---------------------------------------------------------------------------
// cvtW: Wq,Wk,Wv,Wo (1M elems each) fp32 -> bf16 concatenated.
// ---------------------------------------------------------------------------
__global__ __launch_bounds__(256) void cvtW(const float* __restrict__ W0,
                                            const float* __restrict__ W1,
                                            const float* __restrict__ W2,
                                            const float* __restrict__ W3,
                                            u16* __restrict__ dst) {
    const int t     = blockIdx.x * 256 + threadIdx.x;   // 0..512K-1
    const int which = t >> 17;
    const int off   = (t & 0x1FFFF) * 8;
    const float* s  = (which == 0) ? W0 : (which == 1) ? W1 : (which == 2) ? W2 : W3;
    float4 f0 = *(const float4*)(s + off);
    float4 f1 = *(const float4*)(s + off + 4);
    *(bf16x8*)(dst + ((size_t)which << 20) + off) = cvt8(f0, f1);
}

// ---------------------------------------------------------------------------
// Merged Q/K/V GEMM — r13 structure with BK=64 (16 steps instead of 32):
// reg-staged both operands, single-buffered [128][64] LDS (2x16KB),
// 2 barriers/step, 8 waves / 512 thr (wave-tile 64x32), 768 blocks.
// Swizzle: LDS slot x of row r holds k-chunk x^(r&7). Write: chunk (r,s)
// -> slot s^(r&7) (full-row coverage per 8 threads = conflict-free).
// Read: k-chunk ks*4+rowg -> slot (ks*4+rowg)^(colg&7) (2-way max, free).
// ---------------------------------------------------------------------------
__global__ __launch_bounds__(512, 4) void gemm_qkv(const float* __restrict__ q,
                                                   const float* __restrict__ k,
                                                   const float* __restrict__ v,
                                                   const u16* __restrict__ Wb,
                                                   u16* __restrict__ Qp,
                                                   u16* __restrict__ Kp,
                                                   u16* __restrict__ Vt) {
    constexpr int K = 1024, N = 1024;
    __shared__ __align__(16) u16 As[128 * 64];   // 16 KB
    __shared__ __align__(16) u16 Bs[128 * 64];   // 16 KB

    const int tid  = threadIdx.x;
    const int lane = tid & 63;
    const int w    = tid >> 6;          // 0..7
    const int wr = w >> 2, wc = w & 3;  // 2M x 4N wave grid (wave-tile 64x32)
    const int wg    = (blockIdx.x & 7) * 96 + (blockIdx.x >> 3);  // XCD swizzle
    const int which = wg >> 8;
    const int inner = wg & 255;
    const int m0 = (inner >> 3) * 128, n0 = (inner & 7) * 128;
    const int colg = lane & 15, rowg = lane >> 4;

    const float* A = (which == 0) ? q : (which == 1) ? k : v;
    const u16*   W = Wb + ((size_t)which << 20);

    // staging: 1024 chunks (128 rows x 8 slots of 8 elems) per operand;
    // 2 chunks/thread. Global src linear; LDS dest slot s^(row&7).
    size_t aoff[2], boff[2];
    int wio[2];
#pragma unroll
    for (int i = 0; i < 2; ++i) {
        const int c   = i * 512 + tid;
        const int row = c >> 3;
        const int s   = c & 7;
        aoff[i] = (size_t)(m0 + row) * K + s * 8;   // fp32 elems
        boff[i] = (size_t)(n0 + row) * K + s * 8;   // u16 elems
        wio[i]  = row * 64 + (s ^ (row & 7)) * 8;   // u16 index
    }

    // fragment read slots: slot(ks) = (ks*4+rowg) ^ (colg&7)
    const int sl0 = (rowg)     ^ (colg & 7);
    const int sl1 = (4 + rowg) ^ (colg & 7);

    f32x4 acc[4][2];
#pragma unroll
    for (int i = 0; i < 4; ++i)
#pragma unroll
        for (int j = 0; j < 2; ++j) acc[i][j] = (f32x4){0.f, 0.f, 0.f, 0.f};

    for (int t = 0; t < 16; ++t) {
        const int kk = t * 64;
        float4 a0[2], a1[2];
        uint4  bv[2];
#pragma unroll
        for (int i = 0; i < 2; ++i) {
            a0[i] = *(const float4*)(A + aoff[i] + kk);
            a1[i] = *(const float4*)(A + aoff[i] + kk + 4);
            bv[i] = *(const uint4*)(W + boff[i] + kk);
        }
#pragma unroll
        for (int i = 0; i < 2; ++i) {
            *(bf16x8*)(&As[wio[i]]) = cvt8(a0[i], a1[i]);
            *(uint4*)(&Bs[wio[i]]) = bv[i];
        }
        __syncthreads();

#pragma unroll
        for (int ks = 0; ks < 2; ++ks) {
            const int sl = ks ? sl1 : sl0;
            bf16x8 af[4], bfr[2];
#pragma unroll
            for (int mi = 0; mi < 4; ++mi)
                af[mi] = *(const bf16x8*)(&As[(wr * 64 + mi * 16 + colg) * 64 + sl * 8]);
#pragma unroll
            for (int ni = 0; ni < 2; ++ni)
                bfr[ni] = *(const bf16x8*)(&Bs[(wc * 32 + ni * 16 + colg) * 64 + sl * 8]);
#pragma unroll
            for (int mi = 0; mi < 4; ++mi)
#pragma unroll
                for (int ni = 0; ni < 2; ++ni)
                    acc[mi][ni] = mfma16(af[mi], bfr[ni], acc[mi][ni]);
        }
        __syncthreads();
    }

    u16* Crm = (which == 0) ? Qp : Kp;
#pragma unroll
    for (int mi = 0; mi < 4; ++mi) {
#pragma unroll
        for (int ni = 0; ni < 2; ++ni) {
#pragma unroll
            for (int r = 0; r < 4; ++r) {
                const int row = m0 + wr * 64 + mi * 16 + rowg * 4 + r;
                const int col = n0 + wc * 32 + ni * 16 + colg;
                const float vv = acc[mi][ni][r];
                if (which < 2) {
                    Crm[(size_t)row * N + col] = f2bf(vv);
                } else {
                    const int b = row >> 11, tt = row & 2047;
                    const int h = col >> 6,  d = col & 63;
                    Vt[((size_t)((b * 16 + h) * 64 + d) << 11) + tt] = f2bf(vv);
                }
            }
        }
    }
}

// ---------------------------------------------------------------------------
// Output GEMM — r12 version (64x128 tile, 512 blocks, bf16 reg-staged,
// swizzled LDS, 2-phase dbuf pipeline). fp32 out.
// ---------------------------------------------------------------------------
__global__ __launch_bounds__(256) void gemm_out(const u16* __restrict__ Ap,
                                                const u16* __restrict__ W,
                                                float* __restrict__ Cp) {
    constexpr int K = 1024, N = 1024;
    __shared__ __align__(16) u16 As[2][2048];    // 2 x 4 KB
    __shared__ __align__(16) u16 Bs[2][4096];    // 2 x 8 KB

    const int tid  = threadIdx.x;
    const int lane = tid & 63;
    const int w    = tid >> 6;
    const int wr = w >> 1, wc = w & 1;
    const int wg = (blockIdx.x & 7) * 64 + (blockIdx.x >> 3);  // XCD swizzle
    const int m0 = (wg >> 3) * 64, n0 = (wg & 7) * 128;
    const int colg = lane & 15, rowg = lane >> 4;

    const int rowA = tid >> 2, kcA = tid & 3;
    const size_t aoff = (size_t)(m0 + rowA) * K + kcA * 8;
    const int wiA = rowA * 32 + (kcA ^ ((rowA >> 1) & 3)) * 8;

    size_t boff[2];
    int wiB[2];
#pragma unroll
    for (int i = 0; i < 2; ++i) {
        const int c   = i * 256 + tid;
        const int row = c >> 2;
        const int kc  = c & 3;
        boff[i] = (size_t)(n0 + row) * K + kc * 8;
        wiB[i] = row * 32 + (kc ^ ((row >> 1) & 3)) * 8;
    }
    const int kcr   = rowg ^ ((colg >> 1) & 3);
    const int rbase = colg * 32 + kcr * 8;

    f32x4 acc[2][4];
#pragma unroll
    for (int i = 0; i < 2; ++i)
#pragma unroll
        for (int j = 0; j < 4; ++j) acc[i][j] = (f32x4){0.f, 0.f, 0.f, 0.f};

    // prologue
    uint4 av = *(const uint4*)(Ap + aoff);
    uint4 bv[2];
#pragma unroll
    for (int i = 0; i < 2; ++i) bv[i] = *(const uint4*)(W + boff[i]);
    *(uint4*)(&As[0][wiA]) = av;
#pragma unroll
    for (int i = 0; i < 2; ++i) *(uint4*)(&Bs[0][wiB[i]]) = bv[i];
    __syncthreads();

    int p = 0;
    for (int t = 0; t < 32; ++t) {
        if (t < 31) {
            const int kk = (t + 1) * 32;
            av = *(const uint4*)(Ap + aoff + kk);
#pragma unroll
            for (int i = 0; i < 2; ++i) bv[i] = *(const uint4*)(W + boff[i] + kk);
        }
        {
            bf16x8 af[2], bfr[4];
#pragma unroll
            for (int mi = 0; mi < 2; ++mi)
                af[mi] = *(const bf16x8*)(&As[p][(wr * 32 + mi * 16) * 32 + rbase]);
#pragma unroll
            for (int ni = 0; ni < 4; ++ni)
                bfr[ni] = *(const bf16x8*)(&Bs[p][(wc * 64 + ni * 16) * 32 + rbase]);
#pragma unroll
            for (int mi = 0; mi < 2; ++mi)
#pragma unroll
                for (int ni = 0; ni < 4; ++ni)
                    acc[mi][ni] = mfma16(af[mi], bfr[ni], acc[mi][ni]);
        }
        if (t < 31) {
            *(uint4*)(&As[p ^ 1][wiA]) = av;
#pragma unroll
            for (int i = 0; i < 2; ++i) *(uint4*)(&Bs[p ^ 1][wiB[i]]) = bv[i];
        }
        __syncthreads();
        p ^= 1;
    }

#pragma unroll
    for (int mi = 0; mi < 2; ++mi)
#pragma unroll
        for (int ni = 0; ni < 4; ++ni)
#pragma unroll
            for (int r = 0; r < 4; ++r) {
                const int row = m0 + wr * 32 + mi * 16 + rowg * 4 + r;
                const int col = n0 + wc * 64 + ni * 16 + colg;
                Cp[(size_t)row * N + col] = acc[mi][ni][r];
            }
}

// ---------------------------------------------------------------------------
// Flash attention v4 (unchanged from r20): dbuf global_load_lds K/V staging
// with source-permuted addresses, T14 issue-early schedule, swapped QK^T
// lane-local softmax, defer-rescale.
// ---------------------------------------------------------------------------
constexpr float CEXP = 0.18033688011112042f;  // 0.125 * log2(e)

__global__ __launch_bounds__(256) void attn_causal(const u16* __restrict__ Qp,
                                                   const u16* __restrict__ Kp,
                                                   const u16* __restrict__ Vt,
                                                   u16* __restrict__ concat) {
    constexpr int T = 2048, C = 1024;
    __shared__ __align__(16) u16 Ks[2][128 * 64];   // [kv][d] 128B rows
    __shared__ __align__(16) u16 Vs[2][64 * 128];   // [d][kv] 256B rows
    __shared__ __align__(16) u16 Pl[4][2048];       // per-wave P

    const int tid  = threadIdx.x;
    const int lane = tid & 63;
    const int w    = tid >> 6;
    const int colg = lane & 15, rowg = lane >> 4;

    const int idx = blockIdx.x;
    const int xcd = idx & 7;
    const int i1  = idx >> 3;
    const int bh  = xcd * 4 + (i1 & 3);
    const int qg  = 31 - (i1 >> 2);
    const int b = bh >> 4, h = bh & 15;

    const int q0 = (qg * 4 + w) * 16;
    const int nt    = (q0 + 143) >> 7;
    const int ktmax = ((qg * 4 + 3) * 16 + 143) >> 7;

    const u16* Kg = Kp + (size_t)(b * T) * C + h * 64;
    const u16* Vg = Vt + ((size_t)(b * 16 + h) * 64) * T;

    size_t koff[4], voff[4];
    int dofs[4];
#pragma unroll
    for (int i = 0; i < 4; ++i) {
        const int c = i * 256 + tid;
        const int krow = c >> 3;
        const int ksl  = (c & 7) ^ (krow & 7);
        koff[i] = (size_t)krow * C + ksl * 8;
        const int d   = c >> 4;
        const int vsl = (c & 15) ^ (d & 7);
        voff[i] = (size_t)d * T + vsl * 8;
        dofs[i] = c * 8;
    }

    char* Pw = (char*)&Pl[w][0];

    const u16* Qb = Qp + (size_t)(b * T + q0 + colg) * C + h * 64;
    const bf16x8 qf0 = *(const bf16x8*)(Qb + rowg * 8);
    const bf16x8 qf1 = *(const bf16x8*)(Qb + 32 + rowg * 8);

    float mm = -1e30f, ll = 0.f;
    f32x4 O[4];
#pragma unroll
    for (int g = 0; g < 4; ++g) O[g] = (f32x4){0.f, 0.f, 0.f, 0.f};

    const int sw = (colg & 7) << 4;

    // prologue: stage tile 0 into buf 0
#pragma unroll
    for (int i = 0; i < 4; ++i) {
        gload16(Kg + koff[i], &Ks[0][dofs[i]]);
        gload16(Vg + voff[i], &Vs[0][dofs[i]]);
    }
    __syncthreads();

    int buf = 0;
    for (int kt = 0; kt < ktmax; ++kt) {
        if (kt + 1 < ktmax) {
            const size_t kvbn = (size_t)(kt + 1) * 128;
#pragma unroll
            for (int i = 0; i < 4; ++i) {
                gload16(Kg + kvbn * C + koff[i], &Ks[buf ^ 1][dofs[i]]);
                gload16(Vg + kvbn + voff[i], &Vs[buf ^ 1][dofs[i]]);
            }
        }

        if (kt < nt) {
            const int kvb = kt * 128;
            const char* Ksb = (const char*)&Ks[buf][0];
            const char* Vsb = (const char*)&Vs[buf][0];
            float pr[8][4];
#pragma unroll
            for (int sub = 0; sub < 8; ++sub) {
                const int kb = (sub * 16 + colg) * 128 + rowg * 16;
                bf16x8 kf0 = *(const bf16x8*)(Ksb + (kb ^ sw));
                bf16x8 kf1 = *(const bf16x8*)(Ksb + ((kb + 64) ^ sw));
                f32x4 t = (f32x4){0.f, 0.f, 0.f, 0.f};
                t = mfma16(kf0, qf0, t);
                t = mfma16(kf1, qf1, t);
#pragma unroll
                for (int r = 0; r < 4; ++r) pr[sub][r] = t[r];
            }
            if (kvb + 127 > q0) {
#pragma unroll
                for (int sub = 0; sub < 8; ++sub)
#pragma unroll
                    for (int r = 0; r < 4; ++r)
                        if (kvb + sub * 16 + rowg * 4 + r > q0 + colg) pr[sub][r] = -1e30f;
            }
            float mx[8];
#pragma unroll
            for (int sub = 0; sub < 8; ++sub)
                mx[sub] = fmaxf(fmaxf(pr[sub][0], pr[sub][1]), fmaxf(pr[sub][2], pr[sub][3]));
            float pm = fmaxf(fmaxf(fmaxf(mx[0], mx[1]), fmaxf(mx[2], mx[3])),
                             fmaxf(fmaxf(mx[4], mx[5]), fmaxf(mx[6], mx[7])));
            pm = fmaxf(pm, __shfl_xor(pm, 16, 64));
            pm = fmaxf(pm, __shfl_xor(pm, 32, 64));
            if (__any(pm > mm + 40.f)) {
                const float mn = fmaxf(mm, pm);
                const float sc = __builtin_amdgcn_exp2f((mm - mn) * CEXP);
                mm = mn;
                ll *= sc;
#pragma unroll
                for (int r = 0; r < 4; ++r) {
                    const float scr = __shfl(sc, (lane & 48) + rowg * 4 + r, 64);
#pragma unroll
                    for (int g = 0; g < 4; ++g) O[g][r] *= scr;
                }
            }
            float rs = 0.f;
#pragma unroll
            for (int sub = 0; sub < 8; ++sub) {
                const float e0 = __builtin_amdgcn_exp2f((pr[sub][0] - mm) * CEXP);
                const float e1 = __builtin_amdgcn_exp2f((pr[sub][1] - mm) * CEXP);
                const float e2 = __builtin_amdgcn_exp2f((pr[sub][2] - mm) * CEXP);
                const float e3 = __builtin_amdgcn_exp2f((pr[sub][3] - mm) * CEXP);
                pr[sub][0] = e0; pr[sub][1] = e1; pr[sub][2] = e2; pr[sub][3] = e3;
                rs += (e0 + e1) + (e2 + e3);
            }
            rs += __shfl_xor(rs, 16, 64);
            rs += __shfl_xor(rs, 32, 64);
            ll += rs;
#pragma unroll
            for (int sub = 0; sub < 8; ++sub) {
                uint2 pk;
                pk.x = (unsigned)f2bf(pr[sub][0]) | ((unsigned)f2bf(pr[sub][1]) << 16);
                pk.y = (unsigned)f2bf(pr[sub][2]) | ((unsigned)f2bf(pr[sub][3]) << 16);
                const int wb = (colg * 256 + sub * 32 + rowg * 8) ^ sw;
                *(uint2*)(Pw + wb) = pk;
            }
            bf16x8 pf[4];
#pragma unroll
            for (int kc = 0; kc < 4; ++kc)
                pf[kc] = *(const bf16x8*)(Pw + ((colg * 256 + kc * 64 + rowg * 16) ^ sw));
#pragma unroll
            for (int g = 0; g < 4; ++g) {
                const int vb0 = (g * 16 + colg) * 256 + rowg * 16;
#pragma unroll
                for (int kc = 0; kc < 4; ++kc) {
                    bf16x8 vf = *(const bf16x8*)(Vsb + ((vb0 + kc * 64) ^ sw));
                    O[g] = mfma16(pf[kc], vf, O[g]);
                }
            }
        }
        __syncthreads();
        buf ^= 1;
    }

#pragma unroll
    for (int r = 0; r < 4; ++r) {
        const float lr = __shfl(ll, (lane & 48) + rowg * 4 + r, 64);
        const float rc = 1.f / lr;
        const size_t base = (size_t)(b * T + q0 + rowg * 4 + r) * C + h * 64;
#pragma unroll
        for (int g = 0; g < 4; ++g)
            concat[base + g * 16 + colg] = f2bf(O[g][r] * rc);
    }
}

// ---------------------------------------------------------------------------
extern "C" void kernel_launch(void* const* d_in, const int* in_sizes, int n_in,
                              void* d_out, int out_size, void* d_ws, size_t ws_size,
                              hipStream_t stream) {
    const float* q  = (const float*)d_in[0];
    const float* k  = (const float*)d_in[1];
    const float* v  = (const float*)d_in[2];
    const float* Wq = (const float*)d_in[3];
    const float* Wk = (const float*)d_in[4];
    const float* Wv = (const float*)d_in[5];
    const float* Wo = (const float*)d_in[6];
    float* out = (float*)d_out;

    constexpr size_t NELEM = (size_t)4096 * 1024;  // 4M
    constexpr size_t WSZ   = (size_t)1 << 20;      // 1M
    u16* Wbf = (u16*)d_ws;          // bf16 weights    4M
    u16* Qp  = Wbf + 4 * WSZ;       // proj Q          4M
    u16* Kp  = Qp + NELEM;          // proj K          4M
    u16* Vt  = Kp + NELEM;          // proj V (transp) 4M
    u16* Cc  = Vt + NELEM;          // attn concat     4M

    cvtW<<<2048, 256, 0, stream>>>(Wq, Wk, Wv, Wo, Wbf);

    gemm_qkv<<<768, 512, 0, stream>>>(q, k, v, Wbf, Qp, Kp, Vt);

    attn_causal<<<1024, 256, 0, stream>>>(Qp, Kp, Vt, Cc);

    gemm_out<<<512, 256, 0, stream>>>(Cc, Wbf + 3 * WSZ, out);
}